// Round 1
// baseline (539.136 us; speedup 1.0000x reference)
//
#include <hip/hip_runtime.h>

// out[t, 0, d]   = inputs[t, d]
// out[t, l, d]   = memory[l, d]   (l = 1..L-1)
// T=2048, L=64, D=1024, fp32. Write-BW bound (512 MiB of stores).

constexpr int T = 2048;
constexpr int L = 64;
constexpr int D = 1024;

// Work in float4 units. Per output row of D floats -> 256 float4.
// One (t) slab is L*D/4 = 16384 float4.
__global__ __launch_bounds__(256) void sliding_window_memory_kernel(
    const float4* __restrict__ in,    // [T, D/4]
    const float4* __restrict__ mem,   // [L, D/4]
    float4* __restrict__ out)         // [T, L, D/4]
{
    int i = blockIdx.x * blockDim.x + threadIdx.x;   // < T*L*D/4 = 33,554,432
    int t   = i >> 14;          // / 16384
    int rem = i & 16383;        // within slab: l*256 + d4
    int l   = rem >> 8;         // / 256
    int d4  = rem & 255;

    float4 v;
    if (l == 0) {
        v = in[(t << 8) + d4];
    } else {
        v = mem[rem];           // rem = l*256 + d4
    }
    out[i] = v;
}

extern "C" void kernel_launch(void* const* d_in, const int* in_sizes, int n_in,
                              void* d_out, int out_size, void* d_ws, size_t ws_size,
                              hipStream_t stream) {
    const float4* in  = (const float4*)d_in[0];   // inputs [T, D] fp32
    const float4* mem = (const float4*)d_in[1];   // memory [L, D] fp32
    float4* out = (float4*)d_out;                 // [T, L, D] fp32

    const int n4 = T * L * D / 4;                 // 33,554,432
    const int block = 256;
    const int grid = n4 / block;                  // 131,072
    sliding_window_memory_kernel<<<grid, block, 0, stream>>>(in, mem, out);
}